// Round 6
// baseline (322.261 us; speedup 1.0000x reference)
//
#include <hip/hip_runtime.h>
#include <hip/hip_bf16.h>

#define D 128
#define NEG_SLOPE 0.2f
#define SCAN_CHUNK 4096   // elements per block in hierarchical scan

using v8bf16 = __attribute__((ext_vector_type(8))) __bf16;
using f32x4  = __attribute__((ext_vector_type(4))) float;
using v2f    = __attribute__((ext_vector_type(2))) float;

// ---------------- CSR build (one atomic pass) ----------------

// Pass 1: per-edge rank within its destination (the ONLY atomic pass).
__global__ __launch_bounds__(256) void rank_kernel(const int* __restrict__ ei,
        int* __restrict__ cnt, int* __restrict__ rank, int e_in, int n) {
    int e = blockIdx.x * 256 + threadIdx.x;
    int tot = e_in + n;
    if (e >= tot) return;
    int d = (e < e_in) ? ei[e_in + e] : (e - e_in);
    rank[e] = atomicAdd(&cnt[d], 1);
}

__global__ __launch_bounds__(1024) void scan_reduce_kernel(const int* __restrict__ cnt,
        int* __restrict__ blocksum, int n) {
    __shared__ int wsum[16];
    int b = blockIdx.x;
    int base = b * SCAN_CHUNK;
    int t = threadIdx.x;
    int s = 0;
    #pragma unroll
    for (int j = 0; j < 4; ++j) {
        int i = base + t * 4 + j;
        if (i < n) s += cnt[i];
    }
    int lane = t & 63, wid = t >> 6;
    #pragma unroll
    for (int dlt = 32; dlt > 0; dlt >>= 1) s += __shfl_down(s, dlt, 64);
    if (lane == 0) wsum[wid] = s;
    __syncthreads();
    if (t == 0) {
        int tot = 0;
        #pragma unroll
        for (int w = 0; w < 16; ++w) tot += wsum[w];
        blocksum[b] = tot;
    }
}

__global__ __launch_bounds__(1024) void scan_blocksums_kernel(const int* __restrict__ blocksum,
        int* __restrict__ blockoffs, int* __restrict__ offs, int nb, int n) {
    __shared__ int wsum[16];
    __shared__ int carry;
    if (threadIdx.x == 0) carry = 0;
    __syncthreads();
    int lane = threadIdx.x & 63;
    int wid = threadIdx.x >> 6;
    for (int base = 0; base < nb; base += 1024) {
        int i = base + threadIdx.x;
        int v = (i < nb) ? blocksum[i] : 0;
        int x = v;
        #pragma unroll
        for (int dlt = 1; dlt < 64; dlt <<= 1) {
            int y = __shfl_up(x, dlt, 64);
            if (lane >= dlt) x += y;
        }
        if (lane == 63) wsum[wid] = x;
        __syncthreads();
        if (wid == 0) {
            int s = (lane < 16) ? wsum[lane] : 0;
            #pragma unroll
            for (int dlt = 1; dlt < 16; dlt <<= 1) {
                int y = __shfl_up(s, dlt, 64);
                if (lane >= dlt) s += y;
            }
            if (lane < 16) wsum[lane] = s;
        }
        __syncthreads();
        int bincl = x + (wid > 0 ? wsum[wid - 1] : 0);
        int excl = carry + bincl - v;
        if (i < nb) blockoffs[i] = excl;
        __syncthreads();
        if (threadIdx.x == 1023) carry += bincl;
        __syncthreads();
    }
    if (threadIdx.x == 0) { blockoffs[nb] = carry; offs[n] = carry; }
}

__global__ __launch_bounds__(1024) void scan_final_kernel(const int* __restrict__ cnt,
        const int* __restrict__ blockoffs, int* __restrict__ offs, int n) {
    __shared__ int wsum[16];
    int b = blockIdx.x;
    int base = b * SCAN_CHUNK;
    int t = threadIdx.x;
    int i0 = base + t * 4;
    int v[4];
    #pragma unroll
    for (int j = 0; j < 4; ++j) v[j] = (i0 + j < n) ? cnt[i0 + j] : 0;
    int tsum = v[0] + v[1] + v[2] + v[3];
    int lane = t & 63, wid = t >> 6;
    int x = tsum;
    #pragma unroll
    for (int dlt = 1; dlt < 64; dlt <<= 1) {
        int y = __shfl_up(x, dlt, 64);
        if (lane >= dlt) x += y;
    }
    if (lane == 63) wsum[wid] = x;
    __syncthreads();
    if (wid == 0) {
        int s = (lane < 16) ? wsum[lane] : 0;
        #pragma unroll
        for (int dlt = 1; dlt < 16; dlt <<= 1) {
            int y = __shfl_up(s, dlt, 64);
            if (lane >= dlt) s += y;
        }
        if (lane < 16) wsum[lane] = s;
    }
    __syncthreads();
    int incl = x + (wid > 0 ? wsum[wid - 1] : 0);
    int excl = blockoffs[b] + incl - tsum;
    #pragma unroll
    for (int j = 0; j < 4; ++j) {
        if (i0 + j < n) offs[i0 + j] = excl;
        excl += v[j];
    }
}

// Pass 3: atomic-free placement.
__global__ __launch_bounds__(256) void place_kernel(const int* __restrict__ ei,
        const int* __restrict__ offs, const int* __restrict__ rank,
        int* __restrict__ csr_src, int e_in, int n) {
    int e = blockIdx.x * 256 + threadIdx.x;
    int tot = e_in + n;
    if (e >= tot) return;
    int s, d;
    if (e < e_in) { s = ei[e]; d = ei[e_in + e]; }
    else          { s = e - e_in; d = s; }
    csr_src[offs[d] + rank[e]] = s;
}

// ---------------- Per-layer kernels ----------------

// W1,W2 (fp32, [k][c]) -> Wt1,Wt2 (bf16, transposed [c][k]); also zeroes cnt
// (saves the separate memset dispatch; rank_kernel runs after this).
__global__ __launch_bounds__(256) void wcvt_kernel(const float* __restrict__ W1,
        const float* __restrict__ W2, short* __restrict__ Wt1,
        short* __restrict__ Wt2, int* __restrict__ cnt, int n) {
    int t = blockIdx.x * 256 + threadIdx.x;   // 0..32767
    for (int i = t; i < n; i += 32768) cnt[i] = 0;
    int which = t >> 14;
    int idx = t & 16383;
    int k = idx & (D - 1);
    int c = idx >> 7;
    const float* W = which ? W2 : W1;
    short* Wt = which ? Wt2 : Wt1;
    __hip_bfloat16 b = __float2bfloat16(W[(size_t)k * D + c]);
    Wt[(size_t)c * D + k] = *(const short*)&b;
}

// H[n x 128](bf16) = X @ W via mfma_f32_16x16x32_bf16. No LDS, no barriers.
// Fused epilogue from fp32 accumulators: hs = H·a_src, hd = H·a_dst.
template<bool BF16IN>
__global__ __launch_bounds__(256) void gemm_mfma_kernel(
        const void* __restrict__ Xv, const short* __restrict__ Wt,
        const float* __restrict__ a_src, const float* __restrict__ a_dst,
        __hip_bfloat16* __restrict__ H, float* __restrict__ hs,
        float* __restrict__ hd, int n) {
    const int lane = threadIdx.x & 63;
    const int wave = threadIdx.x >> 6;
    const int gl = lane & 15;
    const int q = lane >> 4;
    const int row0 = blockIdx.x * 64 + wave * 16;

    int arow = row0 + gl;
    if (arow >= n) arow = n - 1;   // clamped load; stores are guarded below

    f32x4 acc[8];
    #pragma unroll
    for (int t = 0; t < 8; ++t) acc[t] = (f32x4){0.f, 0.f, 0.f, 0.f};

    #pragma unroll
    for (int kc = 0; kc < 4; ++kc) {
        v8bf16 afr;
        if constexpr (BF16IN) {
            const short* Xb = (const short*)Xv;
            afr = *(const v8bf16*)&Xb[(size_t)arow * D + kc * 32 + q * 8];
        } else {
            const float* Xf = (const float*)Xv;
            const float* p = &Xf[(size_t)arow * D + kc * 32 + q * 8];
            float4 x0 = *(const float4*)p;
            float4 x1 = *(const float4*)(p + 4);
            alignas(16) __hip_bfloat16 hb[8];
            hb[0] = __float2bfloat16(x0.x); hb[1] = __float2bfloat16(x0.y);
            hb[2] = __float2bfloat16(x0.z); hb[3] = __float2bfloat16(x0.w);
            hb[4] = __float2bfloat16(x1.x); hb[5] = __float2bfloat16(x1.y);
            hb[6] = __float2bfloat16(x1.z); hb[7] = __float2bfloat16(x1.w);
            afr = *(const v8bf16*)hb;
        }
        #pragma unroll
        for (int t = 0; t < 8; ++t) {
            v8bf16 bfr = *(const v8bf16*)&Wt[(size_t)(t * 16 + gl) * D + kc * 32 + q * 8];
            acc[t] = __builtin_amdgcn_mfma_f32_16x16x32_bf16(afr, bfr, acc[t], 0, 0, 0);
        }
    }

    float asv[8], adv[8];
    #pragma unroll
    for (int t = 0; t < 8; ++t) { asv[t] = a_src[t * 16 + gl]; adv[t] = a_dst[t * 16 + gl]; }

    // C/D layout: col = t*16 + (lane&15), row = row0 + q*4 + reg
    #pragma unroll
    for (int r = 0; r < 4; ++r) {
        int row = row0 + q * 4 + r;
        bool ok = row < n;
        float ps = 0.f, pd = 0.f;
        #pragma unroll
        for (int t = 0; t < 8; ++t) {
            float v = acc[t][r];
            ps = fmaf(v, asv[t], ps);
            pd = fmaf(v, adv[t], pd);
            if (ok) H[(size_t)row * D + t * 16 + gl] = __float2bfloat16(v);
        }
        #pragma unroll
        for (int dlt = 8; dlt > 0; dlt >>= 1) {
            ps += __shfl_down(ps, dlt, 16);
            pd += __shfl_down(pd, dlt, 16);
        }
        if (ok && gl == 0) { hs[row] = ps; hd[row] = pd; }
    }
}

// Unpack a uint (2 packed bf16) into a packed float2.
__device__ __forceinline__ v2f bf2x(uint u) {
    v2f r;
    r.x = __uint_as_float(u << 16);
    r.y = __uint_as_float(u & 0xffff0000u);
    return r;
}

// Two nodes per 128-thread block, one wave per node; 8 edges in flight per trip
// (lane group grp=lane>>4 owns edges j+2*grp, j+2*grp+1; gl=lane&15 owns 16B of
// the 256B bf16 row). Inactive slots are exec-masked: no gather traffic.
// Accumulation in packed float2 (v_pk_fma_f32).
template<bool OUT_BF16>
__global__ __launch_bounds__(128) void aggregate_kernel(
        const __hip_bfloat16* __restrict__ h, const float* __restrict__ hs,
        const float* __restrict__ hd, const int* __restrict__ offs,
        const int* __restrict__ csr_src, const float* __restrict__ bias,
        float* __restrict__ outf, __hip_bfloat16* __restrict__ outb, int n) {
    int node = blockIdx.x * 2 + (threadIdx.x >> 6);
    if (node >= n) return;
    int lane = threadIdx.x & 63;
    int grp = lane >> 4;
    int gl = lane & 15;
    int beg = offs[node], end = offs[node + 1];
    float hdn = hd[node];
    const uint* hp = (const uint*)h;   // 2 bf16 per uint, row stride 64 uints

    v2f acc[4];
    #pragma unroll
    for (int k = 0; k < 4; ++k) acc[k] = (v2f){0.f, 0.f};
    float z = 0.f;

    for (int j = beg; j < end; j += 8) {
        int jj0 = j + 2 * grp;
        int jj1 = jj0 + 1;
        bool a0 = jj0 < end, a1 = jj1 < end;
        int s0 = a0 ? csr_src[jj0] : 0;
        int s1 = a1 ? csr_src[jj1] : 0;
        float e0 = hs[s0] + hdn;
        float e1 = hs[s1] + hdn;
        e0 = e0 > 0.f ? e0 : NEG_SLOPE * e0;
        e1 = e1 > 0.f ? e1 : NEG_SLOPE * e1;
        float w0 = a0 ? __expf(e0) : 0.f;
        float w1 = a1 ? __expf(e1) : 0.f;
        uint4 r0 = make_uint4(0u, 0u, 0u, 0u);
        uint4 r1 = make_uint4(0u, 0u, 0u, 0u);
        if (a0) r0 = *(const uint4*)(hp + ((size_t)s0 << 6) + (gl << 2));
        if (a1) r1 = *(const uint4*)(hp + ((size_t)s1 << 6) + (gl << 2));
        v2f w0v = (v2f){w0, w0};
        v2f w1v = (v2f){w1, w1};
        acc[0] += bf2x(r0.x) * w0v;
        acc[1] += bf2x(r0.y) * w0v;
        acc[2] += bf2x(r0.z) * w0v;
        acc[3] += bf2x(r0.w) * w0v;
        acc[0] += bf2x(r1.x) * w1v;
        acc[1] += bf2x(r1.y) * w1v;
        acc[2] += bf2x(r1.z) * w1v;
        acc[3] += bf2x(r1.w) * w1v;
        z += w0 + w1;
    }
    // combine the 4 edge groups -> lanes 0..15 hold the full row
    #pragma unroll
    for (int dlt = 32; dlt >= 16; dlt >>= 1) {
        #pragma unroll
        for (int k = 0; k < 4; ++k) {
            acc[k].x += __shfl_down(acc[k].x, dlt, 64);
            acc[k].y += __shfl_down(acc[k].y, dlt, 64);
        }
        z += __shfl_down(z, dlt, 64);
    }
    if (lane < 16) {
        float inv = 1.0f / z;   // self-loop guarantees z > 0
        float4 b0 = *(const float4*)&bias[lane * 8];
        float4 b1 = *(const float4*)&bias[lane * 8 + 4];
        float o[8];
        o[0] = acc[0].x * inv + b0.x; o[1] = acc[0].y * inv + b0.y;
        o[2] = acc[1].x * inv + b0.z; o[3] = acc[1].y * inv + b0.w;
        o[4] = acc[2].x * inv + b1.x; o[5] = acc[2].y * inv + b1.y;
        o[6] = acc[3].x * inv + b1.z; o[7] = acc[3].y * inv + b1.w;
        #pragma unroll
        for (int k = 0; k < 8; ++k) o[k] = o[k] > 0.f ? o[k] : 0.f;
        if constexpr (OUT_BF16) {
            alignas(16) __hip_bfloat16 ob[8];
            #pragma unroll
            for (int k = 0; k < 8; ++k) ob[k] = __float2bfloat16(o[k]);
            *(uint4*)&outb[(size_t)node * D + lane * 8] = *(const uint4*)ob;
        } else {
            float* op = outf + (size_t)node * D + lane * 8;
            *(float4*)op = make_float4(o[0], o[1], o[2], o[3]);
            *(float4*)(op + 4) = make_float4(o[4], o[5], o[6], o[7]);
        }
    }
}

// ---------------- Orchestration ----------------

extern "C" void kernel_launch(void* const* d_in, const int* in_sizes, int n_in,
                              void* d_out, int out_size, void* d_ws, size_t ws_size,
                              hipStream_t stream) {
    const float* x      = (const float*)d_in[0];
    const int*   ei     = (const int*)d_in[1];
    const float* W1     = (const float*)d_in[2];
    const float* a_src1 = (const float*)d_in[3];
    const float* a_dst1 = (const float*)d_in[4];
    const float* b1     = (const float*)d_in[5];
    const float* W2     = (const float*)d_in[6];
    const float* a_src2 = (const float*)d_in[7];
    const float* a_dst2 = (const float*)d_in[8];
    const float* b2     = (const float*)d_in[9];

    int n    = in_sizes[0] / D;       // 100000
    int e_in = in_sizes[1] / 2;       // 625000
    int e_tot = e_in + n;             // 725000
    int nsb = (n + SCAN_CHUNK - 1) / SCAN_CHUNK;

    // ws: h(bf16) | t(bf16) | Wt1 | Wt2 | hs | hd | cnt | offs | rank | blocksum | blockoffs | csr
    __hip_bfloat16* h  = (__hip_bfloat16*)d_ws;
    __hip_bfloat16* tb = h + (size_t)n * D;
    short* Wt1      = (short*)(tb + (size_t)n * D);
    short* Wt2      = Wt1 + D * D;
    float* hs       = (float*)(Wt2 + D * D);
    float* hd       = hs + n;
    int*   cnt      = (int*)(hd + n);
    int*   offs     = cnt + n;
    int*   rank     = offs + n + 1;
    int*   blocksum = rank + e_tot;
    int*   blockoffs= blocksum + nsb;
    int*   csr      = blockoffs + nsb + 1;

    int eb = (e_tot + 255) / 256;
    int nb2 = (n + 1) / 2;
    int gb = (n + 63) / 64;

    wcvt_kernel<<<128, 256, 0, stream>>>(W1, W2, Wt1, Wt2, cnt, n);
    rank_kernel<<<eb, 256, 0, stream>>>(ei, cnt, rank, e_in, n);
    scan_reduce_kernel<<<nsb, 1024, 0, stream>>>(cnt, blocksum, n);
    scan_blocksums_kernel<<<1, 1024, 0, stream>>>(blocksum, blockoffs, offs, nsb, n);
    scan_final_kernel<<<nsb, 1024, 0, stream>>>(cnt, blockoffs, offs, n);
    place_kernel<<<eb, 256, 0, stream>>>(ei, offs, rank, csr, e_in, n);

    // Layer 1
    gemm_mfma_kernel<false><<<gb, 256, 0, stream>>>(x, Wt1, a_src1, a_dst1, h, hs, hd, n);
    aggregate_kernel<true><<<nb2, 128, 0, stream>>>(h, hs, hd, offs, csr, b1, nullptr, tb, n);

    // Layer 2
    gemm_mfma_kernel<true><<<gb, 256, 0, stream>>>(tb, Wt2, a_src2, a_dst2, h, hs, hd, n);
    aggregate_kernel<false><<<nb2, 128, 0, stream>>>(h, hs, hd, offs, csr, b2, (float*)d_out, nullptr, n);
}

// Round 7
// 304.498 us; speedup vs baseline: 1.0583x; 1.0583x over previous
//
#include <hip/hip_runtime.h>
#include <hip/hip_bf16.h>

#define D 128
#define NEG_SLOPE 0.2f
#define SCAN_CHUNK 4096   // elements per block in hierarchical scan

using v8bf16 = __attribute__((ext_vector_type(8))) __bf16;
using f32x4  = __attribute__((ext_vector_type(4))) float;

// ---------------- CSR build (one atomic pass) ----------------

// Pass 1: per-edge rank within its destination (the ONLY atomic pass).
// First 128 blocks also convert W1/W2 -> bf16 transposed (side job; Wt is
// consumed by gemm which runs 3 dispatches later).
__global__ __launch_bounds__(256) void rank_kernel(const int* __restrict__ ei,
        int* __restrict__ cnt, int* __restrict__ rank,
        const float* __restrict__ W1, const float* __restrict__ W2,
        short* __restrict__ Wt1, short* __restrict__ Wt2, int e_in, int n) {
    if (blockIdx.x < 128) {
        int t = blockIdx.x * 256 + threadIdx.x;   // 0..32767
        int which = t >> 14;
        int idx = t & 16383;
        int k = idx & (D - 1);
        int c = idx >> 7;
        const float* W = which ? W2 : W1;
        short* Wt = which ? Wt2 : Wt1;
        __hip_bfloat16 b = __float2bfloat16(W[(size_t)k * D + c]);
        Wt[(size_t)c * D + k] = *(const short*)&b;
    }
    int e = blockIdx.x * 256 + threadIdx.x;
    int tot = e_in + n;
    if (e >= tot) return;
    int d = (e < e_in) ? ei[e_in + e] : (e - e_in);
    rank[e] = atomicAdd(&cnt[d], 1);
}

__global__ __launch_bounds__(1024) void scan_reduce_kernel(const int* __restrict__ cnt,
        int* __restrict__ blocksum, int n) {
    __shared__ int wsum[16];
    int b = blockIdx.x;
    int base = b * SCAN_CHUNK;
    int t = threadIdx.x;
    int s = 0;
    #pragma unroll
    for (int j = 0; j < 4; ++j) {
        int i = base + t * 4 + j;
        if (i < n) s += cnt[i];
    }
    int lane = t & 63, wid = t >> 6;
    #pragma unroll
    for (int dlt = 32; dlt > 0; dlt >>= 1) s += __shfl_down(s, dlt, 64);
    if (lane == 0) wsum[wid] = s;
    __syncthreads();
    if (t == 0) {
        int tot = 0;
        #pragma unroll
        for (int w = 0; w < 16; ++w) tot += wsum[w];
        blocksum[b] = tot;
    }
}

// Per-block exclusive scan of its chunk; block prefix is computed inline from
// blocksum (nsb <= 64). Block 0 also writes offs[n] = grand total.
__global__ __launch_bounds__(1024) void scan_final_kernel(const int* __restrict__ cnt,
        const int* __restrict__ blocksum, int* __restrict__ offs, int nsb, int n) {
    __shared__ int wsum[16];
    __shared__ int sbase, stot;
    int b = blockIdx.x;
    int t = threadIdx.x;
    int lane = t & 63, wid = t >> 6;
    if (wid == 0) {
        int v = (lane < nsb) ? blocksum[lane] : 0;
        int pre = (lane < b) ? v : 0;
        int g = v;
        #pragma unroll
        for (int dlt = 32; dlt > 0; dlt >>= 1) {
            pre += __shfl_down(pre, dlt, 64);
            g += __shfl_down(g, dlt, 64);
        }
        if (lane == 0) { sbase = pre; stot = g; }
    }
    int base = b * SCAN_CHUNK;
    int i0 = base + t * 4;
    int v[4];
    #pragma unroll
    for (int j = 0; j < 4; ++j) v[j] = (i0 + j < n) ? cnt[i0 + j] : 0;
    int tsum = v[0] + v[1] + v[2] + v[3];
    int x = tsum;
    #pragma unroll
    for (int dlt = 1; dlt < 64; dlt <<= 1) {
        int y = __shfl_up(x, dlt, 64);
        if (lane >= dlt) x += y;
    }
    if (lane == 63) wsum[wid] = x;
    __syncthreads();
    if (wid == 0) {
        int s = (lane < 16) ? wsum[lane] : 0;
        #pragma unroll
        for (int dlt = 1; dlt < 16; dlt <<= 1) {
            int y = __shfl_up(s, dlt, 64);
            if (lane >= dlt) s += y;
        }
        if (lane < 16) wsum[lane] = s;
    }
    __syncthreads();
    int incl = x + (wid > 0 ? wsum[wid - 1] : 0);
    int excl = sbase + incl - tsum;
    #pragma unroll
    for (int j = 0; j < 4; ++j) {
        if (i0 + j < n) offs[i0 + j] = excl;
        excl += v[j];
    }
    if (b == 0 && t == 0) offs[n] = stot;
}

// Pass 3: atomic-free placement.
__global__ __launch_bounds__(256) void place_kernel(const int* __restrict__ ei,
        const int* __restrict__ offs, const int* __restrict__ rank,
        int* __restrict__ csr_src, int e_in, int n) {
    int e = blockIdx.x * 256 + threadIdx.x;
    int tot = e_in + n;
    if (e >= tot) return;
    int s, d;
    if (e < e_in) { s = ei[e]; d = ei[e_in + e]; }
    else          { s = e - e_in; d = s; }
    csr_src[offs[d] + rank[e]] = s;
}

// ---------------- Per-layer kernels ----------------

// H[n x 128](bf16) = X @ W via mfma_f32_16x16x32_bf16. No LDS, no barriers.
// Fused epilogue from fp32 accumulators: hs = H·a_src, hd = H·a_dst.
template<bool BF16IN>
__global__ __launch_bounds__(256) void gemm_mfma_kernel(
        const void* __restrict__ Xv, const short* __restrict__ Wt,
        const float* __restrict__ a_src, const float* __restrict__ a_dst,
        __hip_bfloat16* __restrict__ H, float* __restrict__ hs,
        float* __restrict__ hd, int n) {
    const int lane = threadIdx.x & 63;
    const int wave = threadIdx.x >> 6;
    const int gl = lane & 15;
    const int q = lane >> 4;
    const int row0 = blockIdx.x * 64 + wave * 16;

    int arow = row0 + gl;
    if (arow >= n) arow = n - 1;   // clamped load; stores are guarded below

    f32x4 acc[8];
    #pragma unroll
    for (int t = 0; t < 8; ++t) acc[t] = (f32x4){0.f, 0.f, 0.f, 0.f};

    #pragma unroll
    for (int kc = 0; kc < 4; ++kc) {
        v8bf16 afr;
        if constexpr (BF16IN) {
            const short* Xb = (const short*)Xv;
            afr = *(const v8bf16*)&Xb[(size_t)arow * D + kc * 32 + q * 8];
        } else {
            const float* Xf = (const float*)Xv;
            const float* p = &Xf[(size_t)arow * D + kc * 32 + q * 8];
            float4 x0 = *(const float4*)p;
            float4 x1 = *(const float4*)(p + 4);
            alignas(16) __hip_bfloat16 hb[8];
            hb[0] = __float2bfloat16(x0.x); hb[1] = __float2bfloat16(x0.y);
            hb[2] = __float2bfloat16(x0.z); hb[3] = __float2bfloat16(x0.w);
            hb[4] = __float2bfloat16(x1.x); hb[5] = __float2bfloat16(x1.y);
            hb[6] = __float2bfloat16(x1.z); hb[7] = __float2bfloat16(x1.w);
            afr = *(const v8bf16*)hb;
        }
        #pragma unroll
        for (int t = 0; t < 8; ++t) {
            v8bf16 bfr = *(const v8bf16*)&Wt[(size_t)(t * 16 + gl) * D + kc * 32 + q * 8];
            acc[t] = __builtin_amdgcn_mfma_f32_16x16x32_bf16(afr, bfr, acc[t], 0, 0, 0);
        }
    }

    float asv[8], adv[8];
    #pragma unroll
    for (int t = 0; t < 8; ++t) { asv[t] = a_src[t * 16 + gl]; adv[t] = a_dst[t * 16 + gl]; }

    // C/D layout: col = t*16 + (lane&15), row = row0 + q*4 + reg
    #pragma unroll
    for (int r = 0; r < 4; ++r) {
        int row = row0 + q * 4 + r;
        bool ok = row < n;
        float ps = 0.f, pd = 0.f;
        #pragma unroll
        for (int t = 0; t < 8; ++t) {
            float v = acc[t][r];
            ps = fmaf(v, asv[t], ps);
            pd = fmaf(v, adv[t], pd);
            if (ok) H[(size_t)row * D + t * 16 + gl] = __float2bfloat16(v);
        }
        #pragma unroll
        for (int dlt = 8; dlt > 0; dlt >>= 1) {
            ps += __shfl_down(ps, dlt, 16);
            pd += __shfl_down(pd, dlt, 16);
        }
        if (ok && gl == 0) { hs[row] = ps; hd[row] = pd; }
    }
}

// Two nodes per 128-thread block, one wave per node; 12 edges in flight per
// trip (group grp=lane>>4 owns edges j+3*grp..j+3*grp+2; gl=lane&15 owns 16B
// of the 256B bf16 row). Loads are UNCONDITIONAL (fallback = self-loop row,
// already L2-resident — R5 showed masking saves no fetch and breaks load
// clustering); inactive slots contribute w=0.
template<bool OUT_BF16>
__global__ __launch_bounds__(128) void aggregate_kernel(
        const __hip_bfloat16* __restrict__ h, const float* __restrict__ hs,
        const float* __restrict__ hd, const int* __restrict__ offs,
        const int* __restrict__ csr_src, const float* __restrict__ bias,
        float* __restrict__ outf, __hip_bfloat16* __restrict__ outb, int n) {
    int node = blockIdx.x * 2 + (threadIdx.x >> 6);
    if (node >= n) return;
    int lane = threadIdx.x & 63;
    int grp = lane >> 4;
    int gl = lane & 15;
    int beg = offs[node], end = offs[node + 1];
    float hdn = hd[node];
    const uint* hp = (const uint*)h;   // 2 bf16 per uint, row stride 64 uints

    float acc[8] = {0.f, 0.f, 0.f, 0.f, 0.f, 0.f, 0.f, 0.f};
    float z = 0.f;
    for (int j = beg; j < end; j += 12) {
        int jb = j + 3 * grp;
        bool a0 = jb < end, a1 = jb + 1 < end, a2 = jb + 2 < end;
        int s0 = a0 ? csr_src[jb] : node;
        int s1 = a1 ? csr_src[jb + 1] : node;
        int s2 = a2 ? csr_src[jb + 2] : node;
        float e0 = hs[s0] + hdn;
        float e1 = hs[s1] + hdn;
        float e2 = hs[s2] + hdn;
        e0 = e0 > 0.f ? e0 : NEG_SLOPE * e0;
        e1 = e1 > 0.f ? e1 : NEG_SLOPE * e1;
        e2 = e2 > 0.f ? e2 : NEG_SLOPE * e2;
        float w0 = a0 ? __expf(e0) : 0.f;
        float w1 = a1 ? __expf(e1) : 0.f;
        float w2 = a2 ? __expf(e2) : 0.f;
        uint4 r0 = *(const uint4*)(hp + ((size_t)s0 << 6) + (gl << 2));
        uint4 r1 = *(const uint4*)(hp + ((size_t)s1 << 6) + (gl << 2));
        uint4 r2 = *(const uint4*)(hp + ((size_t)s2 << 6) + (gl << 2));
        acc[0] = fmaf(w0, __uint_as_float(r0.x << 16), acc[0]);
        acc[1] = fmaf(w0, __uint_as_float(r0.x & 0xffff0000u), acc[1]);
        acc[2] = fmaf(w0, __uint_as_float(r0.y << 16), acc[2]);
        acc[3] = fmaf(w0, __uint_as_float(r0.y & 0xffff0000u), acc[3]);
        acc[4] = fmaf(w0, __uint_as_float(r0.z << 16), acc[4]);
        acc[5] = fmaf(w0, __uint_as_float(r0.z & 0xffff0000u), acc[5]);
        acc[6] = fmaf(w0, __uint_as_float(r0.w << 16), acc[6]);
        acc[7] = fmaf(w0, __uint_as_float(r0.w & 0xffff0000u), acc[7]);
        acc[0] = fmaf(w1, __uint_as_float(r1.x << 16), acc[0]);
        acc[1] = fmaf(w1, __uint_as_float(r1.x & 0xffff0000u), acc[1]);
        acc[2] = fmaf(w1, __uint_as_float(r1.y << 16), acc[2]);
        acc[3] = fmaf(w1, __uint_as_float(r1.y & 0xffff0000u), acc[3]);
        acc[4] = fmaf(w1, __uint_as_float(r1.z << 16), acc[4]);
        acc[5] = fmaf(w1, __uint_as_float(r1.z & 0xffff0000u), acc[5]);
        acc[6] = fmaf(w1, __uint_as_float(r1.w << 16), acc[6]);
        acc[7] = fmaf(w1, __uint_as_float(r1.w & 0xffff0000u), acc[7]);
        acc[0] = fmaf(w2, __uint_as_float(r2.x << 16), acc[0]);
        acc[1] = fmaf(w2, __uint_as_float(r2.x & 0xffff0000u), acc[1]);
        acc[2] = fmaf(w2, __uint_as_float(r2.y << 16), acc[2]);
        acc[3] = fmaf(w2, __uint_as_float(r2.y & 0xffff0000u), acc[3]);
        acc[4] = fmaf(w2, __uint_as_float(r2.z << 16), acc[4]);
        acc[5] = fmaf(w2, __uint_as_float(r2.z & 0xffff0000u), acc[5]);
        acc[6] = fmaf(w2, __uint_as_float(r2.w << 16), acc[6]);
        acc[7] = fmaf(w2, __uint_as_float(r2.w & 0xffff0000u), acc[7]);
        z += w0 + w1 + w2;
    }
    // combine the 4 edge groups -> lanes 0..15 hold the full row
    #pragma unroll
    for (int dlt = 32; dlt >= 16; dlt >>= 1) {
        #pragma unroll
        for (int k = 0; k < 8; ++k) acc[k] += __shfl_down(acc[k], dlt, 64);
        z += __shfl_down(z, dlt, 64);
    }
    if (lane < 16) {
        float inv = 1.0f / z;   // self-loop guarantees z > 0
        float4 b0 = *(const float4*)&bias[lane * 8];
        float4 b1 = *(const float4*)&bias[lane * 8 + 4];
        float o[8];
        o[0] = acc[0] * inv + b0.x; o[1] = acc[1] * inv + b0.y;
        o[2] = acc[2] * inv + b0.z; o[3] = acc[3] * inv + b0.w;
        o[4] = acc[4] * inv + b1.x; o[5] = acc[5] * inv + b1.y;
        o[6] = acc[6] * inv + b1.z; o[7] = acc[7] * inv + b1.w;
        #pragma unroll
        for (int k = 0; k < 8; ++k) o[k] = o[k] > 0.f ? o[k] : 0.f;
        if constexpr (OUT_BF16) {
            alignas(16) __hip_bfloat16 ob[8];
            #pragma unroll
            for (int k = 0; k < 8; ++k) ob[k] = __float2bfloat16(o[k]);
            *(uint4*)&outb[(size_t)node * D + lane * 8] = *(const uint4*)ob;
        } else {
            float* op = outf + (size_t)node * D + lane * 8;
            *(float4*)op = make_float4(o[0], o[1], o[2], o[3]);
            *(float4*)(op + 4) = make_float4(o[4], o[5], o[6], o[7]);
        }
    }
}

// ---------------- Orchestration ----------------

extern "C" void kernel_launch(void* const* d_in, const int* in_sizes, int n_in,
                              void* d_out, int out_size, void* d_ws, size_t ws_size,
                              hipStream_t stream) {
    const float* x      = (const float*)d_in[0];
    const int*   ei     = (const int*)d_in[1];
    const float* W1     = (const float*)d_in[2];
    const float* a_src1 = (const float*)d_in[3];
    const float* a_dst1 = (const float*)d_in[4];
    const float* b1     = (const float*)d_in[5];
    const float* W2     = (const float*)d_in[6];
    const float* a_src2 = (const float*)d_in[7];
    const float* a_dst2 = (const float*)d_in[8];
    const float* b2     = (const float*)d_in[9];

    int n    = in_sizes[0] / D;       // 100000
    int e_in = in_sizes[1] / 2;       // 625000
    int e_tot = e_in + n;             // 725000
    int nsb = (n + SCAN_CHUNK - 1) / SCAN_CHUNK;   // 25 (must be <= 64)

    // ws: h(bf16) | t(bf16) | Wt1 | Wt2 | hs | hd | cnt | offs | rank | blocksum | csr
    __hip_bfloat16* h  = (__hip_bfloat16*)d_ws;
    __hip_bfloat16* tb = h + (size_t)n * D;
    short* Wt1      = (short*)(tb + (size_t)n * D);
    short* Wt2      = Wt1 + D * D;
    float* hs       = (float*)(Wt2 + D * D);
    float* hd       = hs + n;
    int*   cnt      = (int*)(hd + n);
    int*   offs     = cnt + n;
    int*   rank     = offs + n + 1;
    int*   blocksum = rank + e_tot;
    int*   csr      = blocksum + nsb;

    int eb = (e_tot + 255) / 256;
    int nb2 = (n + 1) / 2;
    int gb = (n + 63) / 64;

    hipMemsetAsync(cnt, 0, (size_t)n * sizeof(int), stream);
    rank_kernel<<<eb, 256, 0, stream>>>(ei, cnt, rank, W1, W2, Wt1, Wt2, e_in, n);
    scan_reduce_kernel<<<nsb, 1024, 0, stream>>>(cnt, blocksum, n);
    scan_final_kernel<<<nsb, 1024, 0, stream>>>(cnt, blocksum, offs, nsb, n);
    place_kernel<<<eb, 256, 0, stream>>>(ei, offs, rank, csr, e_in, n);

    // Layer 1
    gemm_mfma_kernel<false><<<gb, 256, 0, stream>>>(x, Wt1, a_src1, a_dst1, h, hs, hd, n);
    aggregate_kernel<true><<<nb2, 128, 0, stream>>>(h, hs, hd, offs, csr, b1, nullptr, tb, n);

    // Layer 2
    gemm_mfma_kernel<true><<<gb, 256, 0, stream>>>(tb, Wt2, a_src2, a_dst2, h, hs, hd, n);
    aggregate_kernel<false><<<nb2, 128, 0, stream>>>(h, hs, hd, offs, csr, b2, (float*)d_out, nullptr, n);
}

// Round 8
// 293.534 us; speedup vs baseline: 1.0979x; 1.0374x over previous
//
#include <hip/hip_runtime.h>
#include <hip/hip_bf16.h>

#define D 128
#define NEG_SLOPE 0.2f
#define SCAN_CHUNK 4096   // elements per block in hierarchical scan

using v8f16 = __attribute__((ext_vector_type(8))) _Float16;
using v2h   = __attribute__((ext_vector_type(2))) _Float16;
using f32x4 = __attribute__((ext_vector_type(4))) float;

// ---------------- prep: zero cnt + convert W1/W2 -> f16 transposed ----------------

__global__ __launch_bounds__(256) void prep_kernel(const float* __restrict__ W1,
        const float* __restrict__ W2, _Float16* __restrict__ Wt1,
        _Float16* __restrict__ Wt2, int* __restrict__ cnt, int n) {
    int t = blockIdx.x * 256 + threadIdx.x;   // 0..32767
    for (int i = t; i < n; i += 32768) cnt[i] = 0;
    int which = t >> 14;
    int idx = t & 16383;
    int k = idx & (D - 1);
    int c = idx >> 7;
    const float* W = which ? W2 : W1;
    _Float16* Wt = which ? Wt2 : Wt1;
    Wt[(size_t)c * D + k] = (_Float16)W[(size_t)k * D + c];
}

// ---------------- GEMM body (shared by mega1 and gemm2) ----------------

// H[n x 128](f16) = X @ W via mfma_f32_16x16x32_f16. No LDS, no barriers.
// Fused epilogue from fp32 accumulators: hs = H·a_src, hd = H·a_dst.
template<bool F16IN>
__device__ __forceinline__ void gemm_body(int bid, const void* __restrict__ Xv,
        const _Float16* __restrict__ Wt, const float* __restrict__ a_src,
        const float* __restrict__ a_dst, _Float16* __restrict__ H,
        float* __restrict__ hs, float* __restrict__ hd, int n) {
    const int lane = threadIdx.x & 63;
    const int wave = threadIdx.x >> 6;
    const int gl = lane & 15;
    const int q = lane >> 4;
    const int row0 = bid * 64 + wave * 16;

    int arow = row0 + gl;
    if (arow >= n) arow = n - 1;   // clamped load; stores are guarded below

    f32x4 acc[8];
    #pragma unroll
    for (int t = 0; t < 8; ++t) acc[t] = (f32x4){0.f, 0.f, 0.f, 0.f};

    #pragma unroll
    for (int kc = 0; kc < 4; ++kc) {
        v8f16 afr;
        if constexpr (F16IN) {
            const _Float16* Xh = (const _Float16*)Xv;
            afr = *(const v8f16*)&Xh[(size_t)arow * D + kc * 32 + q * 8];
        } else {
            const float* Xf = (const float*)Xv;
            const float* p = &Xf[(size_t)arow * D + kc * 32 + q * 8];
            float4 x0 = *(const float4*)p;
            float4 x1 = *(const float4*)(p + 4);
            afr[0] = (_Float16)x0.x; afr[1] = (_Float16)x0.y;
            afr[2] = (_Float16)x0.z; afr[3] = (_Float16)x0.w;
            afr[4] = (_Float16)x1.x; afr[5] = (_Float16)x1.y;
            afr[6] = (_Float16)x1.z; afr[7] = (_Float16)x1.w;
        }
        #pragma unroll
        for (int t = 0; t < 8; ++t) {
            v8f16 bfr = *(const v8f16*)&Wt[(size_t)(t * 16 + gl) * D + kc * 32 + q * 8];
            acc[t] = __builtin_amdgcn_mfma_f32_16x16x32_f16(afr, bfr, acc[t], 0, 0, 0);
        }
    }

    float asv[8], adv[8];
    #pragma unroll
    for (int t = 0; t < 8; ++t) { asv[t] = a_src[t * 16 + gl]; adv[t] = a_dst[t * 16 + gl]; }

    // C/D layout: col = t*16 + (lane&15), row = row0 + q*4 + reg
    #pragma unroll
    for (int r = 0; r < 4; ++r) {
        int row = row0 + q * 4 + r;
        bool ok = row < n;
        float ps = 0.f, pd = 0.f;
        #pragma unroll
        for (int t = 0; t < 8; ++t) {
            float v = acc[t][r];
            ps = fmaf(v, asv[t], ps);
            pd = fmaf(v, adv[t], pd);
            if (ok) H[(size_t)row * D + t * 16 + gl] = (_Float16)v;
        }
        #pragma unroll
        for (int dlt = 8; dlt > 0; dlt >>= 1) {
            ps += __shfl_down(ps, dlt, 16);
            pd += __shfl_down(pd, dlt, 16);
        }
        if (ok && gl == 0) { hs[row] = ps; hd[row] = pd; }
    }
}

// ---------------- mega1: GEMM1 (blocks [0,gb)) ∥ rank (blocks [gb, gb+eb)) ----------------
// Independent work items fused into one dispatch so the latency-bound atomic
// pass and the memory-bound GEMM share the machine.

__global__ __launch_bounds__(256) void mega1_kernel(
        const float* __restrict__ x, const _Float16* __restrict__ Wt1,
        const float* __restrict__ a_src1, const float* __restrict__ a_dst1,
        _Float16* __restrict__ h, float* __restrict__ hs, float* __restrict__ hd,
        const int* __restrict__ ei, int* __restrict__ cnt, int* __restrict__ rank,
        int gb, int e_in, int n) {
    int b = blockIdx.x;
    if (b < gb) {
        gemm_body<false>(b, x, Wt1, a_src1, a_dst1, h, hs, hd, n);
        return;
    }
    int e = (b - gb) * 256 + threadIdx.x;
    int tot = e_in + n;
    if (e >= tot) return;
    int d = (e < e_in) ? ei[e_in + e] : (e - e_in);
    rank[e] = atomicAdd(&cnt[d], 1);
}

__global__ __launch_bounds__(256) void gemm2_kernel(
        const _Float16* __restrict__ tb, const _Float16* __restrict__ Wt2,
        const float* __restrict__ a_src2, const float* __restrict__ a_dst2,
        _Float16* __restrict__ h, float* __restrict__ hs, float* __restrict__ hd,
        int n) {
    gemm_body<true>(blockIdx.x, tb, Wt2, a_src2, a_dst2, h, hs, hd, n);
}

// ---------------- scans ----------------

__global__ __launch_bounds__(1024) void scan_reduce_kernel(const int* __restrict__ cnt,
        int* __restrict__ blocksum, int n) {
    __shared__ int wsum[16];
    int b = blockIdx.x;
    int base = b * SCAN_CHUNK;
    int t = threadIdx.x;
    int s = 0;
    #pragma unroll
    for (int j = 0; j < 4; ++j) {
        int i = base + t * 4 + j;
        if (i < n) s += cnt[i];
    }
    int lane = t & 63, wid = t >> 6;
    #pragma unroll
    for (int dlt = 32; dlt > 0; dlt >>= 1) s += __shfl_down(s, dlt, 64);
    if (lane == 0) wsum[wid] = s;
    __syncthreads();
    if (t == 0) {
        int tot = 0;
        #pragma unroll
        for (int w = 0; w < 16; ++w) tot += wsum[w];
        blocksum[b] = tot;
    }
}

// Per-block exclusive scan of its chunk; block prefix computed inline from
// blocksum (nsb <= 64). Block 0 also writes offs[n] = grand total.
__global__ __launch_bounds__(1024) void scan_final_kernel(const int* __restrict__ cnt,
        const int* __restrict__ blocksum, int* __restrict__ offs, int nsb, int n) {
    __shared__ int wsum[16];
    __shared__ int sbase, stot;
    int b = blockIdx.x;
    int t = threadIdx.x;
    int lane = t & 63, wid = t >> 6;
    if (wid == 0) {
        int v = (lane < nsb) ? blocksum[lane] : 0;
        int pre = (lane < b) ? v : 0;
        int g = v;
        #pragma unroll
        for (int dlt = 32; dlt > 0; dlt >>= 1) {
            pre += __shfl_down(pre, dlt, 64);
            g += __shfl_down(g, dlt, 64);
        }
        if (lane == 0) { sbase = pre; stot = g; }
    }
    int base = b * SCAN_CHUNK;
    int i0 = base + t * 4;
    int v[4];
    #pragma unroll
    for (int j = 0; j < 4; ++j) v[j] = (i0 + j < n) ? cnt[i0 + j] : 0;
    int tsum = v[0] + v[1] + v[2] + v[3];
    int x = tsum;
    #pragma unroll
    for (int dlt = 1; dlt < 64; dlt <<= 1) {
        int y = __shfl_up(x, dlt, 64);
        if (lane >= dlt) x += y;
    }
    if (lane == 63) wsum[wid] = x;
    __syncthreads();
    if (wid == 0) {
        int s = (lane < 16) ? wsum[lane] : 0;
        #pragma unroll
        for (int dlt = 1; dlt < 16; dlt <<= 1) {
            int y = __shfl_up(s, dlt, 64);
            if (lane >= dlt) s += y;
        }
        if (lane < 16) wsum[lane] = s;
    }
    __syncthreads();
    int incl = x + (wid > 0 ? wsum[wid - 1] : 0);
    int excl = sbase + incl - tsum;
    #pragma unroll
    for (int j = 0; j < 4; ++j) {
        if (i0 + j < n) offs[i0 + j] = excl;
        excl += v[j];
    }
    if (b == 0 && t == 0) offs[n] = stot;
}

// atomic-free placement.
__global__ __launch_bounds__(256) void place_kernel(const int* __restrict__ ei,
        const int* __restrict__ offs, const int* __restrict__ rank,
        int* __restrict__ csr_src, int e_in, int n) {
    int e = blockIdx.x * 256 + threadIdx.x;
    int tot = e_in + n;
    if (e >= tot) return;
    int s, d;
    if (e < e_in) { s = ei[e]; d = ei[e_in + e]; }
    else          { s = e - e_in; d = s; }
    csr_src[offs[d] + rank[e]] = s;
}

// ---------------- aggregate ----------------

__device__ __forceinline__ v2h pack_lo(uint a, uint b) {
    v2h r;
    r.x = __builtin_bit_cast(_Float16, (unsigned short)(a & 0xffffu));
    r.y = __builtin_bit_cast(_Float16, (unsigned short)(b & 0xffffu));
    return r;
}
__device__ __forceinline__ v2h pack_hi(uint a, uint b) {
    v2h r;
    r.x = __builtin_bit_cast(_Float16, (unsigned short)(a >> 16));
    r.y = __builtin_bit_cast(_Float16, (unsigned short)(b >> 16));
    return r;
}
__device__ __forceinline__ float lo_f(uint a) {
    return (float)__builtin_bit_cast(_Float16, (unsigned short)(a & 0xffffu));
}
__device__ __forceinline__ float hi_f(uint a) {
    return (float)__builtin_bit_cast(_Float16, (unsigned short)(a >> 16));
}

// Two nodes per 128-thread block, one wave per node; 12 edges in flight per
// trip (group grp=lane>>4 owns edges j+3*grp..j+3*grp+2; gl=lane&15 owns 16B
// of the 256B f16 row). Loads unconditional (fallback = self-loop row, already
// L2-resident); inactive slots contribute w=0. Edge pair (e0,e1) accumulates
// via v_dot2_f32_f16; e2 via scalar cvt+fma.
template<bool OUT_F16>
__global__ __launch_bounds__(128) void aggregate_kernel(
        const _Float16* __restrict__ h, const float* __restrict__ hs,
        const float* __restrict__ hd, const int* __restrict__ offs,
        const int* __restrict__ csr_src, const float* __restrict__ bias,
        float* __restrict__ outf, _Float16* __restrict__ outb, int n) {
    int node = blockIdx.x * 2 + (threadIdx.x >> 6);
    if (node >= n) return;
    int lane = threadIdx.x & 63;
    int grp = lane >> 4;
    int gl = lane & 15;
    int beg = offs[node], end = offs[node + 1];
    float hdn = hd[node];
    const uint* hp = (const uint*)h;   // 2 f16 per uint, row stride 64 uints

    float acc[8] = {0.f, 0.f, 0.f, 0.f, 0.f, 0.f, 0.f, 0.f};
    float z = 0.f;
    for (int j = beg; j < end; j += 12) {
        int jb = j + 3 * grp;
        bool a0 = jb < end, a1 = jb + 1 < end, a2 = jb + 2 < end;
        int s0 = a0 ? csr_src[jb] : node;
        int s1 = a1 ? csr_src[jb + 1] : node;
        int s2 = a2 ? csr_src[jb + 2] : node;
        float e0 = hs[s0] + hdn;
        float e1 = hs[s1] + hdn;
        float e2 = hs[s2] + hdn;
        e0 = e0 > 0.f ? e0 : NEG_SLOPE * e0;
        e1 = e1 > 0.f ? e1 : NEG_SLOPE * e1;
        e2 = e2 > 0.f ? e2 : NEG_SLOPE * e2;
        float w0 = a0 ? __expf(e0) : 0.f;
        float w1 = a1 ? __expf(e1) : 0.f;
        float w2 = a2 ? __expf(e2) : 0.f;
        uint4 r0 = *(const uint4*)(hp + ((size_t)s0 << 6) + (gl << 2));
        uint4 r1 = *(const uint4*)(hp + ((size_t)s1 << 6) + (gl << 2));
        uint4 r2 = *(const uint4*)(hp + ((size_t)s2 << 6) + (gl << 2));
#if __has_builtin(__builtin_amdgcn_fdot2)
        v2h w01; w01.x = (_Float16)w0; w01.y = (_Float16)w1;
        acc[0] = __builtin_amdgcn_fdot2(pack_lo(r0.x, r1.x), w01, acc[0], false);
        acc[1] = __builtin_amdgcn_fdot2(pack_hi(r0.x, r1.x), w01, acc[1], false);
        acc[2] = __builtin_amdgcn_fdot2(pack_lo(r0.y, r1.y), w01, acc[2], false);
        acc[3] = __builtin_amdgcn_fdot2(pack_hi(r0.y, r1.y), w01, acc[3], false);
        acc[4] = __builtin_amdgcn_fdot2(pack_lo(r0.z, r1.z), w01, acc[4], false);
        acc[5] = __builtin_amdgcn_fdot2(pack_hi(r0.z, r1.z), w01, acc[5], false);
        acc[6] = __builtin_amdgcn_fdot2(pack_lo(r0.w, r1.w), w01, acc[6], false);
        acc[7] = __builtin_amdgcn_fdot2(pack_hi(r0.w, r1.w), w01, acc[7], false);
#else
        acc[0] = fmaf(w0, lo_f(r0.x), acc[0]); acc[1] = fmaf(w0, hi_f(r0.x), acc[1]);
        acc[2] = fmaf(w0, lo_f(r0.y), acc[2]); acc[3] = fmaf(w0, hi_f(r0.y), acc[3]);
        acc[4] = fmaf(w0, lo_f(r0.z), acc[4]); acc[5] = fmaf(w0, hi_f(r0.z), acc[5]);
        acc[6] = fmaf(w0, lo_f(r0.w), acc[6]); acc[7] = fmaf(w0, hi_f(r0.w), acc[7]);
        acc[0] = fmaf(w1, lo_f(r1.x), acc[0]); acc[1] = fmaf(w1, hi_f(r1.x), acc[1]);
        acc[2] = fmaf(w1, lo_f(r1.y), acc[2]); acc[3] = fmaf(w1, hi_f(r1.y), acc[3]);
        acc[4] = fmaf(w1, lo_f(r1.z), acc[4]); acc[5] = fmaf(w1, hi_f(r1.z), acc[5]);
        acc[6] = fmaf(w1, lo_f(r1.w), acc[6]); acc[7] = fmaf(w1, hi_f(r1.w), acc[7]);
#endif
        acc[0] = fmaf(w2, lo_f(r2.x), acc[0]); acc[1] = fmaf(w2, hi_f(r2.x), acc[1]);
        acc[2] = fmaf(w2, lo_f(r2.y), acc[2]); acc[3] = fmaf(w2, hi_f(r2.y), acc[3]);
        acc[4] = fmaf(w2, lo_f(r2.z), acc[4]); acc[5] = fmaf(w2, hi_f(r2.z), acc[5]);
        acc[6] = fmaf(w2, lo_f(r2.w), acc[6]); acc[7] = fmaf(w2, hi_f(r2.w), acc[7]);
        z += w0 + w1 + w2;
    }
    // combine the 4 edge groups -> lanes 0..15 hold the full row
    #pragma unroll
    for (int dlt = 32; dlt >= 16; dlt >>= 1) {
        #pragma unroll
        for (int k = 0; k < 8; ++k) acc[k] += __shfl_down(acc[k], dlt, 64);
        z += __shfl_down(z, dlt, 64);
    }
    if (lane < 16) {
        float inv = 1.0f / z;   // self-loop guarantees z > 0
        float4 b0 = *(const float4*)&bias[lane * 8];
        float4 b1 = *(const float4*)&bias[lane * 8 + 4];
        float o[8];
        o[0] = acc[0] * inv + b0.x; o[1] = acc[1] * inv + b0.y;
        o[2] = acc[2] * inv + b0.z; o[3] = acc[3] * inv + b0.w;
        o[4] = acc[4] * inv + b1.x; o[5] = acc[5] * inv + b1.y;
        o[6] = acc[6] * inv + b1.z; o[7] = acc[7] * inv + b1.w;
        #pragma unroll
        for (int k = 0; k < 8; ++k) o[k] = o[k] > 0.f ? o[k] : 0.f;
        if constexpr (OUT_F16) {
            alignas(16) _Float16 ob[8];
            #pragma unroll
            for (int k = 0; k < 8; ++k) ob[k] = (_Float16)o[k];
            *(uint4*)&outb[(size_t)node * D + lane * 8] = *(const uint4*)ob;
        } else {
            float* op = outf + (size_t)node * D + lane * 8;
            *(float4*)op = make_float4(o[0], o[1], o[2], o[3]);
            *(float4*)(op + 4) = make_float4(o[4], o[5], o[6], o[7]);
        }
    }
}

// ---------------- Orchestration ----------------

extern "C" void kernel_launch(void* const* d_in, const int* in_sizes, int n_in,
                              void* d_out, int out_size, void* d_ws, size_t ws_size,
                              hipStream_t stream) {
    const float* x      = (const float*)d_in[0];
    const int*   ei     = (const int*)d_in[1];
    const float* W1     = (const float*)d_in[2];
    const float* a_src1 = (const float*)d_in[3];
    const float* a_dst1 = (const float*)d_in[4];
    const float* b1     = (const float*)d_in[5];
    const float* W2     = (const float*)d_in[6];
    const float* a_src2 = (const float*)d_in[7];
    const float* a_dst2 = (const float*)d_in[8];
    const float* b2     = (const float*)d_in[9];

    int n    = in_sizes[0] / D;       // 100000
    int e_in = in_sizes[1] / 2;       // 625000
    int e_tot = e_in + n;             // 725000
    int nsb = (n + SCAN_CHUNK - 1) / SCAN_CHUNK;   // 25 (must be <= 64)

    // ws: h(f16) | t(f16) | Wt1 | Wt2 | hs | hd | cnt | offs | rank | blocksum | csr
    _Float16* h  = (_Float16*)d_ws;
    _Float16* tb = h + (size_t)n * D;
    _Float16* Wt1 = tb + (size_t)n * D;
    _Float16* Wt2 = Wt1 + D * D;
    float* hs       = (float*)(Wt2 + D * D);
    float* hd       = hs + n;
    int*   cnt      = (int*)(hd + n);
    int*   offs     = cnt + n;
    int*   rank     = offs + n + 1;
    int*   blocksum = rank + e_tot;
    int*   csr      = blocksum + nsb;

    int eb = (e_tot + 255) / 256;
    int nb2 = (n + 1) / 2;
    int gb = (n + 63) / 64;

    prep_kernel<<<128, 256, 0, stream>>>(W1, W2, Wt1, Wt2, cnt, n);
    mega1_kernel<<<gb + eb, 256, 0, stream>>>(x, Wt1, a_src1, a_dst1, h, hs, hd,
                                              ei, cnt, rank, gb, e_in, n);
    scan_reduce_kernel<<<nsb, 1024, 0, stream>>>(cnt, blocksum, n);
    scan_final_kernel<<<nsb, 1024, 0, stream>>>(cnt, blocksum, offs, nsb, n);
    place_kernel<<<eb, 256, 0, stream>>>(ei, offs, rank, csr, e_in, n);

    aggregate_kernel<true><<<nb2, 128, 0, stream>>>(h, hs, hd, offs, csr, b1, nullptr, tb, n);
    gemm2_kernel<<<gb, 256, 0, stream>>>(tb, Wt2, a_src2, a_dst2, h, hs, hd, n);
    aggregate_kernel<false><<<nb2, 128, 0, stream>>>(h, hs, hd, offs, csr, b2, (float*)d_out, nullptr, n);
}